// Round 3
// baseline (278.592 us; speedup 1.0000x reference)
//
#include <hip/hip_runtime.h>

#define HH 256
#define WW 256
#define TT 32
#define TI 8
#define NW 8            // waves per block
#define CHUNK 16
#define PLANE (HH * WW)
#define PROWS (TI + 4)  // 12
#define KROWS (TI + 2)  // 10

struct alignas(16) F4 { float x, y, z, w; };
__device__ inline F4 operator+(F4 a, F4 b) { return {a.x+b.x, a.y+b.y, a.z+b.z, a.w+b.w}; }
__device__ inline F4 operator-(F4 a, F4 b) { return {a.x-b.x, a.y-b.y, a.z-b.z, a.w-b.w}; }
__device__ inline F4 operator*(F4 a, F4 b) { return {a.x*b.x, a.y*b.y, a.z*b.z, a.w*b.w}; }
__device__ inline F4 operator*(F4 a, float s) { return {a.x*s, a.y*s, a.z*s, a.w*s}; }
__device__ inline F4 operator*(float s, F4 a) { return {a.x*s, a.y*s, a.z*s, a.w*s}; }

// async global->LDS, 16B per lane; LDS dest = wave-uniform base + lane*16
__device__ __forceinline__ void gload16(const float* g, float* l) {
  __builtin_amdgcn_global_load_lds(
      (const __attribute__((address_space(1))) void*)g,
      (__attribute__((address_space(3))) void*)l, 16, 0, 0);
}

__global__ __launch_bounds__(512, 6) void pil_main(const float* __restrict__ p,
                                                   const float* __restrict__ Kf,
                                                   double* __restrict__ ws) {
  __shared__ float sP[2][PROWS][WW];   // 2 x 12 x 256 x 4B = 24 KB
  __shared__ float sK[2][KROWS][WW];   // 2 x 10 x 256 x 4B = 20 KB
  __shared__ double redN[NW];
  __shared__ int redD[NW];

  const int tile = blockIdx.x;    // 0..31
  const int b = blockIdx.y;       // 0..15
  const int chunk = blockIdx.z;   // 0..1
  const int t0 = chunk * CHUNK;
  const int tstart = (chunk == 0) ? 0 : (t0 - 1);
  const int tend = (chunk == 0) ? (t0 + CHUNK) : (TT - 1);
  const int cmplT = (t0 == 0) ? 2 : (t0 + 1);

  const int i0 = tile * TI;
  const int tid = threadIdx.x;
  const int r = tid >> 6;          // row within tile (wave-uniform)
  const int g = tid & 63;
  const int j0 = g << 2;
  const int i = i0 + r;
  const int wid = tid >> 6;
  const int lane = tid & 63;

  const float i2hx = 0.02f;        // 1/(2*25)
  const float i2hy = 0.01f;        // 1/(2*50)
  const float Sc = 2e-4f;

  float cm2[4] = {0, 0, 0, 0}, cm1[4] = {0, 0, 0, 0};
  float dkA[4] = {0, 0, 0, 0}, dkB[4] = {0, 0, 0, 0};
  float mA[4] = {0, 0, 0, 0}, mB[4] = {0, 0, 0, 0};
  double accN = 0.0;
  int accD = 0;

  const size_t bbase = (size_t)b * TT * PLANE;

  // ---- precomputed staging slots: wave `wid` owns rows idx = wid, wid+8, wid+16 ----
  // idx 0..11  -> p rows i0-2+idx ; idx 12..21 -> K rows i0-1+(idx-12)
  const float* gcur[3];
  float* ldA[3];
  float* ldB[3];
  bool vld[3], slotK[3];
#pragma unroll
  for (int s = 0; s < 3; ++s) {
    int idx = wid + NW * s;
    bool isK = (idx >= PROWS);
    int row = isK ? (i0 - 1 + (idx - PROWS)) : (i0 - 2 + idx);
    bool v = (idx < PROWS + KROWS) && (row >= 0) && (row < HH);
    slotK[s] = isK;
    vld[s] = v;
    const float* basep = isK ? Kf : p;
    gcur[s] = basep + bbase + (size_t)tstart * PLANE +
              (size_t)(v ? row : 0) * WW + (lane << 2);
    ldA[s] = isK ? &sK[0][idx - PROWS][0] : &sP[0][idx][0];
    ldB[s] = isK ? &sK[1][idx - PROWS][0] : &sP[1][idx][0];
  }

  // ---- prologue: stage plane tstart into buffer 0 ----
  {
    bool k0 = (tstart >= t0) && (tstart < t0 + CHUNK);
#pragma unroll
    for (int s = 0; s < 3; ++s)
      if (vld[s] && (k0 || !slotK[s])) gload16(gcur[s], ldA[s]);
#pragma unroll
    for (int s = 0; s < 3; ++s) gcur[s] += PLANE;
  }
  __syncthreads();

#pragma unroll 1
  for (int t = tstart; t <= tend; ++t) {
    const int cur = (t - tstart) & 1;
    float (*sPc)[WW] = sP[cur];
    float (*sKc)[WW] = sK[cur];
    const bool do_divk = (t >= t0) && (t < t0 + CHUNK);
    const int li = i - i0 + 2;
    const int liK = i - i0 + 1;

    // ======== phase 1: ALL ds_reads for this plane (before any DMA issue) ========
    float cTa[4], divka[4] = {0, 0, 0, 0}, ma[4] = {0, 0, 0, 0};
    F4 pdx4, t14, pdxx4, kdx4, kc0v, pc0v;
    F4 pLv, pRv, kLv, kRv;

    if (do_divk) {
      auto LP = [&](int gr) -> F4 {
        return *reinterpret_cast<const F4*>(&sPc[gr - i0 + 2][j0]);
      };
      auto LK = [&](int gr) -> F4 {
        return *reinterpret_cast<const F4*>(&sKc[gr - i0 + 1][j0]);
      };

      // ---- row-direction terms (reads + math; branches wave-uniform) ----
      if (i >= 2 && i <= HH - 3) {
        F4 r0 = LP(i - 2), r1 = LP(i - 1), r2 = LP(i), r3 = LP(i + 1), r4 = LP(i + 2);
        F4 km = LK(i - 1), kc = LK(i), kp = LK(i + 1);
        F4 gm = (r2 - r0) * i2hx;
        F4 gp = (r4 - r2) * i2hx;
        pdx4 = (r3 - r1) * i2hx;
        t14 = (kp * gp - km * gm) * i2hx;
        pdxx4 = (gp - gm) * i2hx;
        kdx4 = (kp - km) * i2hx;
        kc0v = kc; pc0v = r2;
      } else if (i == 0) {
        F4 a0 = LP(0), a1 = LP(1), a2 = LP(2), a3 = LP(3);
        F4 k0 = LK(0), k1 = LK(1), k2 = LK(2);
        F4 g0 = (4.0f * a1 - 3.0f * a0 - a2) * i2hx;
        F4 g1 = (a2 - a0) * i2hx;
        F4 g2 = (a3 - a1) * i2hx;
        pdx4 = g0;
        t14 = (4.0f * (k1 * g1) - 3.0f * (k0 * g0) - k2 * g2) * i2hx;
        pdxx4 = (4.0f * g1 - 3.0f * g0 - g2) * i2hx;
        kdx4 = (4.0f * k1 - 3.0f * k0 - k2) * i2hx;
        kc0v = k0; pc0v = a0;
      } else if (i == 1) {
        F4 a0 = LP(0), a1 = LP(1), a2 = LP(2), a3 = LP(3);
        F4 k0 = LK(0), k2 = LK(2), k1 = LK(1);
        F4 gm = (4.0f * a1 - 3.0f * a0 - a2) * i2hx;  // g(0) edge
        F4 gp = (a3 - a1) * i2hx;                      // g(2)
        pdx4 = (a2 - a0) * i2hx;
        t14 = (k2 * gp - k0 * gm) * i2hx;
        pdxx4 = (gp - gm) * i2hx;
        kdx4 = (k2 - k0) * i2hx;
        kc0v = k1; pc0v = a1;
      } else if (i == HH - 2) {  // 254
        F4 a0 = LP(HH - 4), a1 = LP(HH - 3), a2 = LP(HH - 2), a3 = LP(HH - 1);
        F4 k3 = LK(HH - 3), kcen = LK(HH - 2), kN = LK(HH - 1);
        F4 gm = (a2 - a0) * i2hx;                       // g(253)
        F4 gp = (3.0f * a3 - 4.0f * a2 + a1) * i2hx;    // g(255) edge
        pdx4 = (a3 - a1) * i2hx;
        t14 = (kN * gp - k3 * gm) * i2hx;
        pdxx4 = (gp - gm) * i2hx;
        kdx4 = (kN - k3) * i2hx;
        kc0v = kcen; pc0v = a2;
      } else {  // i == 255
        F4 a0 = LP(HH - 4), a1 = LP(HH - 3), a2 = LP(HH - 2), a3 = LP(HH - 1);
        F4 k3 = LK(HH - 3), k4 = LK(HH - 2), kN = LK(HH - 1);
        F4 gm2 = (a2 - a0) * i2hx;                      // g(253)
        F4 gm1 = (a3 - a1) * i2hx;                      // g(254)
        F4 gN = (3.0f * a3 - 4.0f * a2 + a1) * i2hx;    // g(255) edge
        pdx4 = gN;
        t14 = (3.0f * (kN * gN) - 4.0f * (k4 * gm1) + k3 * gm2) * i2hx;
        pdxx4 = (3.0f * gN - 4.0f * gm1 + gm2) * i2hx;
        kdx4 = (3.0f * kN - 4.0f * k4 + k3) * i2hx;
        kc0v = kN; pc0v = a3;
      }
      cTa[0] = pc0v.x; cTa[1] = pc0v.y; cTa[2] = pc0v.z; cTa[3] = pc0v.w;

      // column-neighborhood reads
      const int jL = (j0 >= 4) ? (j0 - 4) : 0;
      const int jR = (j0 + 4 <= WW - 4) ? (j0 + 4) : (WW - 4);
      pLv = *reinterpret_cast<const F4*>(&sPc[li][jL]);
      pRv = *reinterpret_cast<const F4*>(&sPc[li][jR]);
      kLv = *reinterpret_cast<const F4*>(&sKc[liK][jL]);
      kRv = *reinterpret_cast<const F4*>(&sKc[liK][jR]);
    } else {
      F4 c4 = *reinterpret_cast<const F4*>(&sPc[li][j0]);
      cTa[0] = c4.x; cTa[1] = c4.y; cTa[2] = c4.z; cTa[3] = c4.w;
    }

    // ======== phase 2: issue DMA for plane t+1 (after all ds_reads) ========
    if (t < tend) {
      bool nK = (t + 1 >= t0) && (t + 1 < t0 + CHUNK);
#pragma unroll
      for (int s = 0; s < 3; ++s)
        if (vld[s] && (nK || !slotK[s]))
          gload16(gcur[s], (cur == 0) ? ldB[s] : ldA[s]);
#pragma unroll
      for (int s = 0; s < 3; ++s) gcur[s] += PLANE;
    }

    // ======== phase 3: pure-register compute ========
    if (do_divk) {
      float pc[12] = {pLv.x, pLv.y, pLv.z, pLv.w, pc0v.x, pc0v.y, pc0v.z, pc0v.w,
                      pRv.x, pRv.y, pRv.z, pRv.w};
      float kcA[12] = {kLv.x, kLv.y, kLv.z, kLv.w, kc0v.x, kc0v.y, kc0v.z, kc0v.w,
                       kRv.x, kRv.y, kRv.z, kRv.w};
      float pdxa[4] = {pdx4.x, pdx4.y, pdx4.z, pdx4.w};
      float t1a[4] = {t14.x, t14.y, t14.z, t14.w};
      float pdxxa[4] = {pdxx4.x, pdxx4.y, pdxx4.z, pdxx4.w};
      float kdxa[4] = {kdx4.x, kdx4.y, kdx4.z, kdx4.w};

#pragma unroll
      for (int q = 0; q < 4; ++q) {
        const int j = j0 + q;
        float pdy, t2, pdyy, kdy;
        if (j >= 2 && j <= WW - 3) {
          float gm = (pc[4 + q] - pc[2 + q]) * i2hy;
          float gp = (pc[6 + q] - pc[4 + q]) * i2hy;
          pdy = (pc[5 + q] - pc[3 + q]) * i2hy;
          t2 = (kcA[5 + q] * gp - kcA[3 + q] * gm) * i2hy;
          pdyy = (gp - gm) * i2hy;
          kdy = (kcA[5 + q] - kcA[3 + q]) * i2hy;
        } else if (j == 0) {
          float g0 = (4.0f * pc[5] - 3.0f * pc[4] - pc[6]) * i2hy;
          float g1 = (pc[6] - pc[4]) * i2hy;
          float g2 = (pc[7] - pc[5]) * i2hy;
          pdy = g0;
          t2 = (4.0f * (kcA[5] * g1) - 3.0f * (kcA[4] * g0) - kcA[6] * g2) * i2hy;
          pdyy = (4.0f * g1 - 3.0f * g0 - g2) * i2hy;
          kdy = (4.0f * kcA[5] - 3.0f * kcA[4] - kcA[6]) * i2hy;
        } else if (j == 1) {
          float gm = (4.0f * pc[5] - 3.0f * pc[4] - pc[6]) * i2hy;
          float gp = (pc[7] - pc[5]) * i2hy;
          pdy = (pc[6] - pc[4]) * i2hy;
          t2 = (kcA[6] * gp - kcA[4] * gm) * i2hy;
          pdyy = (gp - gm) * i2hy;
          kdy = (kcA[6] - kcA[4]) * i2hy;
        } else if (j == WW - 2) {
          float gm = (pc[6] - pc[4]) * i2hy;
          float gp = (3.0f * pc[7] - 4.0f * pc[6] + pc[5]) * i2hy;
          pdy = (pc[7] - pc[5]) * i2hy;
          t2 = (kcA[7] * gp - kcA[5] * gm) * i2hy;
          pdyy = (gp - gm) * i2hy;
          kdy = (kcA[7] - kcA[5]) * i2hy;
        } else {  // j == 255
          float gm2 = (pc[6] - pc[4]) * i2hy;
          float gm1 = (pc[7] - pc[5]) * i2hy;
          float gN = (3.0f * pc[7] - 4.0f * pc[6] + pc[5]) * i2hy;
          pdy = gN;
          t2 = (3.0f * (kcA[7] * gN) - 4.0f * (kcA[6] * gm1) + kcA[5] * gm2) * i2hy;
          pdyy = (3.0f * gN - 4.0f * gm1 + gm2) * i2hy;
          kdy = (3.0f * kcA[7] - 4.0f * kcA[6] + kcA[5]) * i2hy;
        }

        divka[q] = t1a[q] + t2;
        float divk2 = (pdxxa[q] + pdyy) * kcA[4 + q] + pdxa[q] * kdxa[q] + pdy * kdy;
        ma[q] = (fabsf(divka[q] - divk2) < 100.0f) ? 1.0f : 0.0f;
      }
    }

    // ---- deferred time-gradient completion + rolling update ----
    float pn = 0.0f;
    int pd = 0;
#pragma unroll
    for (int q = 0; q < 4; ++q) {
      const float cT = cTa[q];
      if (t >= cmplT) {
        float pdt = (cT - cm2[q]) * 0.5f;
        float d = dkB[q] - pdt * Sc;
        pn += d * d * mB[q];
        pd += (int)mB[q];
        if (t0 == 0 && t == 2) {
          float pdt0 = (4.0f * cm1[q] - 3.0f * cm2[q] - cT) * 0.5f;
          float d0 = dkA[q] - pdt0 * Sc;
          pn += d0 * d0 * mA[q];
          pd += (int)mA[q];
        }
      }
      if (t == TT - 1) {
        float pdtN = (3.0f * cT - 4.0f * cm1[q] + cm2[q]) * 0.5f;
        float dN = divka[q] - pdtN * Sc;
        pn += dN * dN * ma[q];
        pd += (int)ma[q];
      }
      if (do_divk) {
        dkA[q] = dkB[q]; mA[q] = mB[q];
        dkB[q] = divka[q]; mB[q] = ma[q];
      }
      cm2[q] = cm1[q]; cm1[q] = cT;
    }
    accN += (double)pn;
    accD += pd;

    __syncthreads();  // waves done reading buf[cur]; next-plane DMA drained
  }

  // ---- block reduction ----
  for (int off = 32; off > 0; off >>= 1) {
    accN += __shfl_down(accN, off);
    accD += __shfl_down(accD, off);
  }
  if ((tid & 63) == 0) { redN[wid] = accN; redD[wid] = accD; }
  __syncthreads();
  if (tid == 0) {
    double n = 0.0; long long dd = 0;
    for (int w = 0; w < NW; ++w) { n += redN[w]; dd += redD[w]; }
    const int slot = (b * 32 + tile) * 2 + chunk;   // = b*64 + tile*2 + chunk
    ws[slot] = n;
    ws[1024 + slot] = (double)dd;
  }
}

__global__ void pil_final(const double* __restrict__ ws, float* __restrict__ out) {
  __shared__ double s[16];
  const int tid = threadIdx.x;  // 1024 threads: tid = b*64 + (tile*2 + chunk)
  double n = ws[tid];
  double d = ws[1024 + tid];
  for (int off = 32; off > 0; off >>= 1) {
    n += __shfl_down(n, off);
    d += __shfl_down(d, off);
  }
  if ((tid & 63) == 0) s[tid >> 6] = n / d;   // wave w == batch w
  __syncthreads();
  if (tid == 0) {
    double acc = 0.0;
    for (int bb = 0; bb < 16; ++bb) acc += s[bb];
    out[0] = (float)(acc / 16.0);
  }
}

extern "C" void kernel_launch(void* const* d_in, const int* in_sizes, int n_in,
                              void* d_out, int out_size, void* d_ws, size_t ws_size,
                              hipStream_t stream) {
  const float* p = (const float*)d_in[0];
  const float* K = (const float*)d_in[1];
  double* ws = (double*)d_ws;
  float* out = (float*)d_out;
  dim3 grid(HH / TI, 16, 2);  // (32 tiles, 16 batches, 2 T-chunks) = 1024 blocks
  pil_main<<<grid, 512, 0, stream>>>(p, K, ws);
  pil_final<<<1, 1024, 0, stream>>>(ws, out);
}

// Round 4
// 78.484 us; speedup vs baseline: 3.5497x; 3.5497x over previous
//
#include <hip/hip_runtime.h>

#define HH 256
#define WW 256
#define TT 32
#define PLANE (HH * WW)
#define CHUNK 16

struct alignas(16) F4 { float x, y, z, w; };
__device__ inline F4 operator+(F4 a, F4 b) { return {a.x+b.x, a.y+b.y, a.z+b.z, a.w+b.w}; }
__device__ inline F4 operator-(F4 a, F4 b) { return {a.x-b.x, a.y-b.y, a.z-b.z, a.w-b.w}; }
__device__ inline F4 operator*(F4 a, F4 b) { return {a.x*b.x, a.y*b.y, a.z*b.z, a.w*b.w}; }
__device__ inline F4 operator*(F4 a, float s) { return {a.x*s, a.y*s, a.z*s, a.w*s}; }
__device__ inline F4 operator*(float s, F4 a) { return {a.x*s, a.y*s, a.z*s, a.w*s}; }

__global__ __launch_bounds__(256, 4) void pil_main(const float* __restrict__ p,
                                                   const float* __restrict__ Kf,
                                                   double* __restrict__ ws) {
  __shared__ double redN[4];
  __shared__ int redD[4];

  const int rg = blockIdx.x;      // row group 0..63 (4 rows per block)
  const int b = blockIdx.y;       // 0..15
  const int chunk = blockIdx.z;   // 0..1
  const int t0 = chunk * CHUNK;
  const int tstart = (chunk == 0) ? 0 : (t0 - 1);
  const int tend = (chunk == 0) ? (t0 + CHUNK) : (TT - 1);
  const int cmplT = (t0 == 0) ? 2 : (t0 + 1);

  const int tid = threadIdx.x;
  const int wid = tid >> 6;       // wave index = row within group
  const int lane = tid & 63;
  const int i = (rg << 2) + wid;  // global row (wave-uniform)
  const int j0 = lane << 2;       // first of 4 cols

  const float i2hx = 0.02f;       // 1/(2*25)
  const float i2hy = 0.01f;       // 1/(2*50)
  const float Sc = 2e-4f;

  // rolling per-point state (4 cols/thread)
  float cm2[4] = {0, 0, 0, 0}, cm1[4] = {0, 0, 0, 0};
  float dkA[4] = {0, 0, 0, 0}, dkB[4] = {0, 0, 0, 0};
  unsigned mAb = 0, mBb = 0;      // mask bits, bit q = col j0+q
  double accN = 0.0;
  int accD = 0;

  const size_t bbase = (size_t)b * TT * PLANE;

  // clamped row windows (wave-uniform)
  int pa = i - 2; pa = pa < 0 ? 0 : pa; pa = pa > HH - 5 ? HH - 5 : pa;  // p rows pa..pa+4
  int ka = i - 1; ka = ka < 0 ? 0 : ka; ka = ka > HH - 3 ? HH - 3 : ka;  // K rows ka..ka+2
  // rowcase: 0 interior, 1: i==0, 2: i==1, 3: i==254, 4: i==255
  const int rowcase = (i >= 2 && i <= HH - 3) ? 0
                      : (i == 0 ? 1 : (i == 1 ? 2 : (i == HH - 2 ? 3 : 4)));

  const float* pr0 = p + bbase + (size_t)tstart * PLANE + (size_t)pa * WW + j0;
  const float* pr1 = pr0 + WW;
  const float* pr2 = pr0 + 2 * WW;
  const float* pr3 = pr0 + 3 * WW;
  const float* pr4 = pr0 + 4 * WW;
  const float* kr0 = Kf + bbase + (size_t)tstart * PLANE + (size_t)ka * WW + j0;
  const float* kr1 = kr0 + WW;
  const float* kr2 = kr0 + 2 * WW;
  const float* pcp = p + bbase + (size_t)tstart * PLANE + (size_t)i * WW + j0;  // halo iters

#pragma unroll 1
  for (int t = tstart; t <= tend; ++t) {
    const bool dk = (t >= t0) && (t < t0 + CHUNK);

    F4 pcen, kcen;
    F4 r0v, r1v, r2v, r3v, r4v, kAv, kBv, kCv;
    float divka[4] = {0, 0, 0, 0};
    unsigned mcur = 0;
    F4 pdx4, t14, pdxx4, kdx4;

    if (dk) {  // 8 independent coalesced 16B loads
      r0v = *reinterpret_cast<const F4*>(pr0);
      r1v = *reinterpret_cast<const F4*>(pr1);
      r2v = *reinterpret_cast<const F4*>(pr2);
      r3v = *reinterpret_cast<const F4*>(pr3);
      r4v = *reinterpret_cast<const F4*>(pr4);
      kAv = *reinterpret_cast<const F4*>(kr0);
      kBv = *reinterpret_cast<const F4*>(kr1);
      kCv = *reinterpret_cast<const F4*>(kr2);
    } else {   // halo plane: only center row needed (for p_dt state)
      pcen = *reinterpret_cast<const F4*>(pcp);
    }
    pr0 += PLANE; pr1 += PLANE; pr2 += PLANE; pr3 += PLANE; pr4 += PLANE;
    kr0 += PLANE; kr1 += PLANE; kr2 += PLANE; pcp += PLANE;

    if (dk) {
      // ---- x-direction terms (wave-uniform rowcase branch) ----
      if (rowcase == 0) {  // interior: r0..r4 = rows i-2..i+2; kA,kB,kC = i-1,i,i+1
        F4 gm = (r2v - r0v) * i2hx;
        F4 gp = (r4v - r2v) * i2hx;
        pdx4 = (r3v - r1v) * i2hx;
        t14 = (kCv * gp - kAv * gm) * i2hx;
        pdxx4 = (gp - gm) * i2hx;
        kdx4 = (kCv - kAv) * i2hx;
        kcen = kBv; pcen = r2v;
      } else if (rowcase == 1) {  // i==0: rows r0..r3 = 0..3; kA,kB,kC = 0,1,2
        F4 g0 = (4.0f * r1v - 3.0f * r0v - r2v) * i2hx;
        F4 g1 = (r2v - r0v) * i2hx;
        F4 g2 = (r3v - r1v) * i2hx;
        pdx4 = g0;
        t14 = (4.0f * (kBv * g1) - 3.0f * (kAv * g0) - kCv * g2) * i2hx;
        pdxx4 = (4.0f * g1 - 3.0f * g0 - g2) * i2hx;
        kdx4 = (4.0f * kBv - 3.0f * kAv - kCv) * i2hx;
        kcen = kAv; pcen = r0v;
      } else if (rowcase == 2) {  // i==1: rows r0..r3 = 0..3; kA,kB,kC = 0,1,2
        F4 gm = (4.0f * r1v - 3.0f * r0v - r2v) * i2hx;  // g(0) edge
        F4 gp = (r3v - r1v) * i2hx;                       // g(2)
        pdx4 = (r2v - r0v) * i2hx;
        t14 = (kCv * gp - kAv * gm) * i2hx;
        pdxx4 = (gp - gm) * i2hx;
        kdx4 = (kCv - kAv) * i2hx;
        kcen = kBv; pcen = r1v;
      } else if (rowcase == 3) {  // i==254: rows r1..r4 = 252..255; kA,kB,kC = 253,254,255
        F4 gm = (r3v - r1v) * i2hx;                        // g(253)
        F4 gp = (3.0f * r4v - 4.0f * r3v + r2v) * i2hx;    // g(255) edge
        pdx4 = (r4v - r2v) * i2hx;
        t14 = (kCv * gp - kAv * gm) * i2hx;
        pdxx4 = (gp - gm) * i2hx;
        kdx4 = (kCv - kAv) * i2hx;
        kcen = kBv; pcen = r3v;
      } else {  // i==255: rows r1..r4 = 252..255; kA,kB,kC = 253,254,255
        F4 gm2 = (r3v - r1v) * i2hx;                       // g(253)
        F4 gm1 = (r4v - r2v) * i2hx;                       // g(254)
        F4 gN = (3.0f * r4v - 4.0f * r3v + r2v) * i2hx;    // g(255) edge
        pdx4 = gN;
        t14 = (3.0f * (kCv * gN) - 4.0f * (kBv * gm1) + kAv * gm2) * i2hx;
        pdxx4 = (3.0f * gN - 4.0f * gm1 + gm2) * i2hx;
        kdx4 = (3.0f * kCv - 4.0f * kBv + kAv) * i2hx;
        kcen = kCv; pcen = r4v;
      }

      // ---- neighbor columns via cross-lane shuffles (whole wave active) ----
      float pm2 = __shfl_up(pcen.z, 1);    // col j0-2
      float pm1 = __shfl_up(pcen.w, 1);    // col j0-1
      float pp4 = __shfl_down(pcen.x, 1);  // col j0+4
      float pp5 = __shfl_down(pcen.y, 1);  // col j0+5
      float km1 = __shfl_up(kcen.w, 1);    // col j0-1
      float kp4 = __shfl_down(kcen.x, 1);  // col j0+4

      float pcy[8] = {pm2, pm1, pcen.x, pcen.y, pcen.z, pcen.w, pp4, pp5}; // cols j0-2..j0+5
      float kcy[6] = {km1, kcen.x, kcen.y, kcen.z, kcen.w, kp4};           // cols j0-1..j0+4
      float pdxa[4] = {pdx4.x, pdx4.y, pdx4.z, pdx4.w};
      float t1a[4] = {t14.x, t14.y, t14.z, t14.w};
      float pdxxa[4] = {pdxx4.x, pdxx4.y, pdxx4.z, pdxx4.w};
      float kdxa[4] = {kdx4.x, kdx4.y, kdx4.z, kdx4.w};

#pragma unroll
      for (int q = 0; q < 4; ++q) {
        float pdy, t2, pdyy, kdy;
        const bool edgeL = (j0 == 0) && (q <= 1);
        const bool edgeR = (j0 == WW - 4) && (q >= 2);
        if (!edgeL && !edgeR) {  // interior col
          float gm = (pcy[2 + q] - pcy[0 + q]) * i2hy;
          float gp = (pcy[4 + q] - pcy[2 + q]) * i2hy;
          pdy = (pcy[3 + q] - pcy[1 + q]) * i2hy;
          t2 = (kcy[2 + q] * gp - kcy[q] * gm) * i2hy;
          pdyy = (gp - gm) * i2hy;
          kdy = (kcy[2 + q] - kcy[q]) * i2hy;
        } else if (edgeL && q == 0) {  // j==0
          float g0 = (4.0f * pcy[3] - 3.0f * pcy[2] - pcy[4]) * i2hy;
          float g1 = (pcy[4] - pcy[2]) * i2hy;
          float g2 = (pcy[5] - pcy[3]) * i2hy;
          pdy = g0;
          t2 = (4.0f * (kcy[2] * g1) - 3.0f * (kcy[1] * g0) - kcy[3] * g2) * i2hy;
          pdyy = (4.0f * g1 - 3.0f * g0 - g2) * i2hy;
          kdy = (4.0f * kcy[2] - 3.0f * kcy[1] - kcy[3]) * i2hy;
        } else if (edgeL) {  // j==1
          float gm = (4.0f * pcy[3] - 3.0f * pcy[2] - pcy[4]) * i2hy;  // gy(0)
          float gp = (pcy[5] - pcy[3]) * i2hy;                          // gy(2)
          pdy = (pcy[4] - pcy[2]) * i2hy;
          t2 = (kcy[3] * gp - kcy[1] * gm) * i2hy;
          pdyy = (gp - gm) * i2hy;
          kdy = (kcy[3] - kcy[1]) * i2hy;
        } else if (q == 2) {  // j==254
          float gm = (pcy[4] - pcy[2]) * i2hy;                          // gy(253)
          float gp = (3.0f * pcy[5] - 4.0f * pcy[4] + pcy[3]) * i2hy;   // gy(255)
          pdy = (pcy[5] - pcy[3]) * i2hy;
          t2 = (kcy[4] * gp - kcy[2] * gm) * i2hy;
          pdyy = (gp - gm) * i2hy;
          kdy = (kcy[4] - kcy[2]) * i2hy;
        } else {  // j==255
          float gm2 = (pcy[4] - pcy[2]) * i2hy;
          float gm1 = (pcy[5] - pcy[3]) * i2hy;
          float gN = (3.0f * pcy[5] - 4.0f * pcy[4] + pcy[3]) * i2hy;
          pdy = gN;
          t2 = (3.0f * (kcy[4] * gN) - 4.0f * (kcy[3] * gm1) + kcy[2] * gm2) * i2hy;
          pdyy = (3.0f * gN - 4.0f * gm1 + gm2) * i2hy;
          kdy = (3.0f * kcy[4] - 4.0f * kcy[3] + kcy[2]) * i2hy;
        }

        divka[q] = t1a[q] + t2;
        float divk2 = (pdxxa[q] + pdyy) * kcy[1 + q] + pdxa[q] * kdxa[q] + pdy * kdy;
        mcur |= (fabsf(divka[q] - divk2) < 100.0f) ? (1u << q) : 0u;
      }
    }

    // ---- deferred time-gradient completion + state roll ----
    float cTa[4] = {pcen.x, pcen.y, pcen.z, pcen.w};
    float pn = 0.0f;
    int pd = 0;
#pragma unroll
    for (int q = 0; q < 4; ++q) {
      const float cT = cTa[q];
      if (t >= cmplT) {
        // plane t-1 interior: p_dt = (c(t) - c(t-2))/2
        float pdt = (cT - cm2[q]) * 0.5f;
        float d = dkB[q] - pdt * Sc;
        if (mBb & (1u << q)) { pn += d * d; pd += 1; }
        if (t0 == 0 && t == 2) {
          // plane 0 edge: p_dt = (-3c0 + 4c1 - c2)/2
          float pdt0 = (4.0f * cm1[q] - 3.0f * cm2[q] - cT) * 0.5f;
          float d0 = dkA[q] - pdt0 * Sc;
          if (mAb & (1u << q)) { pn += d0 * d0; pd += 1; }
        }
      }
      if (t == TT - 1) {
        // plane 31 edge: p_dt = (3c31 - 4c30 + c29)/2
        float pdtN = (3.0f * cT - 4.0f * cm1[q] + cm2[q]) * 0.5f;
        float dN = divka[q] - pdtN * Sc;
        if (mcur & (1u << q)) { pn += dN * dN; pd += 1; }
      }
      if (dk) { dkA[q] = dkB[q]; dkB[q] = divka[q]; }
      cm2[q] = cm1[q]; cm1[q] = cT;
    }
    if (dk) { mAb = mBb; mBb = mcur; }
    accN += (double)pn;
    accD += pd;
  }

  // ---- wave + block reduction ----
  for (int off = 32; off > 0; off >>= 1) {
    accN += __shfl_down(accN, off);
    accD += __shfl_down(accD, off);
  }
  if (lane == 0) { redN[wid] = accN; redD[wid] = accD; }
  __syncthreads();
  if (tid == 0) {
    double n = 0.0; long long dd = 0;
    for (int w = 0; w < 4; ++w) { n += redN[w]; dd += redD[w]; }
    const int slot = (b << 7) + (rg << 1) + chunk;   // b*128 + rg*2 + chunk
    ws[slot] = n;
    ws[2048 + slot] = (double)dd;
  }
}

__global__ void pil_final(const double* __restrict__ ws, float* __restrict__ out) {
  __shared__ double s[16];
  const int tid = threadIdx.x;   // 256 threads
  const int b = tid >> 4;        // batch 0..15
  const int k = tid & 15;        // 16 threads per batch, 8 slots each
  double n = 0.0, d = 0.0;
  const int base = (b << 7) + (k << 3);
#pragma unroll
  for (int sidx = 0; sidx < 8; ++sidx) {
    n += ws[base + sidx];
    d += ws[2048 + base + sidx];
  }
  for (int off = 8; off > 0; off >>= 1) {
    n += __shfl_down(n, off, 16);
    d += __shfl_down(d, off, 16);
  }
  if (k == 0) s[b] = n / d;
  __syncthreads();
  if (tid == 0) {
    double acc = 0.0;
    for (int bb = 0; bb < 16; ++bb) acc += s[bb];
    out[0] = (float)(acc / 16.0);
  }
}

extern "C" void kernel_launch(void* const* d_in, const int* in_sizes, int n_in,
                              void* d_out, int out_size, void* d_ws, size_t ws_size,
                              hipStream_t stream) {
  const float* p = (const float*)d_in[0];
  const float* K = (const float*)d_in[1];
  double* ws = (double*)d_ws;
  float* out = (float*)d_out;
  dim3 grid(HH / 4, 16, 2);  // (64 row-groups, 16 batches, 2 T-chunks) = 2048 blocks
  pil_main<<<grid, 256, 0, stream>>>(p, K, ws);
  pil_final<<<1, 256, 0, stream>>>(ws, out);
}